// Round 1
// baseline (228.436 us; speedup 1.0000x reference)
//
#include <hip/hip_runtime.h>
#include <hip/hip_fp16.h>

// Flash-attention for DotProductAttention: B=16, Lq=Lk=2048, D=128, fp32 in/out.
// Per-batch valid_lens masks key positions >= len (ref uses -1e6 -> exact zeros).
// Strategy: f16 MFMA (16x16x32), skip fully-masked K-tiles, online softmax.

typedef _Float16 f16x8 __attribute__((ext_vector_type(8)));
typedef float f32x4 __attribute__((ext_vector_type(4)));

#define LQ 2048
#define LK 2048
#define DIM 128
#define KTILE 32
#define QTILE 32   // 2 waves x 16 rows
#define NW 2

__device__ __forceinline__ f16x8 cvt8(const float4 a, const float4 b) {
    f16x8 r;
    r[0]=(_Float16)a.x; r[1]=(_Float16)a.y; r[2]=(_Float16)a.z; r[3]=(_Float16)a.w;
    r[4]=(_Float16)b.x; r[5]=(_Float16)b.y; r[6]=(_Float16)b.z; r[7]=(_Float16)b.w;
    return r;
}

__global__ __launch_bounds__(128, 2)
void fa_kernel(const float* __restrict__ Qg, const float* __restrict__ Kg,
               const float* __restrict__ Vg, const int* __restrict__ VLg,
               float* __restrict__ Og)
{
    // K tile, XOR-swizzled row-major [32][128] f16: byte = (row*256 + d*2) ^ ((row&7)<<4)
    __shared__ __align__(16) _Float16 ldsK[KTILE * DIM];
    // V^T tile [d=128][key stride 40] (80B row stride -> ~2-way banks, free)
    __shared__ __align__(16) _Float16 ldsVT[DIM * 40];
    // Per-wave P scratch [16 q][stride 40]
    __shared__ __align__(16) _Float16 ldsP[NW][16 * 40];

    const int tid  = threadIdx.x;
    const int wv   = tid >> 6;
    const int lane = tid & 63;
    const int lg   = lane >> 4;   // 0..3
    const int ln   = lane & 15;

    const int blk = blockIdx.x;
    const int b   = blk >> 6;          // 64 q-tiles per batch
    const int qt  = blk & 63;
    const int q0  = qt * QTILE + wv * 16;

    const int nvalid = VLg[b];                         // 1..2048
    const int ntiles = (nvalid + KTILE - 1) >> 5;      // skip fully-masked tiles (exact)

    // fold 1/sqrt(128) and log2(e) so we can use native exp2
    const float SCL = 0.08838834764831845f * 1.44269504088896341f;

    // ---- Q fragments (A-layout): lane holds Q[q0+ln][dc*32 + lg*8 + j] ----
    f16x8 qf[4];
    {
        const float* qrow = Qg + ((size_t)b * LQ + q0 + ln) * DIM + lg * 8;
        #pragma unroll
        for (int dc = 0; dc < 4; ++dc) {
            float4 a = *(const float4*)(qrow + dc * 32);
            float4 c = *(const float4*)(qrow + dc * 32 + 4);
            qf[dc] = cvt8(a, c);
        }
    }

    f32x4 acc[8];
    #pragma unroll
    for (int t = 0; t < 8; ++t) acc[t] = (f32x4){0.f, 0.f, 0.f, 0.f};
    float mrow[4] = {-INFINITY, -INFINITY, -INFINITY, -INFINITY};
    float lrow[4] = {0.f, 0.f, 0.f, 0.f};

    char* ldsKb = (char*)ldsK;
    _Float16* myP = &ldsP[wv][0];

    for (int kt = 0; kt < ntiles; ++kt) {
        const int k0 = kt * KTILE;
        __syncthreads();   // protect LDS tiles from previous iteration's readers

        // ---- stage K tile (global fp32 -> f16, swizzled) ----
        #pragma unroll
        for (int i = 0; i < 4; ++i) {
            int c = tid + i * 128;
            int row = c >> 4, d0 = (c & 15) * 8;
            const float* src = Kg + ((size_t)b * LK + k0 + row) * DIM + d0;
            float4 a = *(const float4*)src;
            float4 d = *(const float4*)(src + 4);
            *(f16x8*)(ldsKb + ((row * 256 + d0 * 2) ^ ((row & 7) << 4))) = cvt8(a, d);
        }
        // ---- stage V transposed: ldsVT[d][key] ----
        #pragma unroll
        for (int i = 0; i < 4; ++i) {
            int c = tid + i * 128;
            int key = c & 31, d0 = (c >> 5) * 8;
            const float* src = Vg + ((size_t)b * LK + k0 + key) * DIM + d0;
            float4 a = *(const float4*)src;
            float4 d = *(const float4*)(src + 4);
            _Float16* dst = &ldsVT[d0 * 40 + key];
            dst[0*40] = (_Float16)a.x; dst[1*40] = (_Float16)a.y;
            dst[2*40] = (_Float16)a.z; dst[3*40] = (_Float16)a.w;
            dst[4*40] = (_Float16)d.x; dst[5*40] = (_Float16)d.y;
            dst[6*40] = (_Float16)d.z; dst[7*40] = (_Float16)d.w;
        }
        __syncthreads();

        // ---- S = Q K^T for 16 q-rows x 32 keys (two 16x16 col-tiles) ----
        f32x4 s0 = {0.f,0.f,0.f,0.f}, s1 = {0.f,0.f,0.f,0.f};
        #pragma unroll
        for (int dc = 0; dc < 4; ++dc) {
            int off = dc * 64 + lg * 16;  // byte offset of d-chunk within a K row
            f16x8 b0 = *(const f16x8*)(ldsKb + ((ln        * 256 + off) ^ ((ln & 7) << 4)));
            f16x8 b1 = *(const f16x8*)(ldsKb + (((16 + ln) * 256 + off) ^ ((ln & 7) << 4)));
            s0 = __builtin_amdgcn_mfma_f32_16x16x32_f16(qf[dc], b0, s0, 0, 0, 0);
            s1 = __builtin_amdgcn_mfma_f32_16x16x32_f16(qf[dc], b1, s1, 0, 0, 0);
        }

        // ---- scale (+ boundary mask) ----
        #pragma unroll
        for (int r = 0; r < 4; ++r) { s0[r] *= SCL; s1[r] *= SCL; }
        if (k0 + KTILE > nvalid) {
            if (k0 + ln >= nvalid)      { s0[0]=s0[1]=s0[2]=s0[3] = -1e30f; }
            if (k0 + 16 + ln >= nvalid) { s1[0]=s1[1]=s1[2]=s1[3] = -1e30f; }
        }

        // ---- online softmax: row stats live in 16-lane groups ----
        float pm[4];
        #pragma unroll
        for (int r = 0; r < 4; ++r) pm[r] = fmaxf(s0[r], s1[r]);
        #pragma unroll
        for (int off = 1; off < 16; off <<= 1) {
            #pragma unroll
            for (int r = 0; r < 4; ++r) pm[r] = fmaxf(pm[r], __shfl_xor(pm[r], off));
        }
        float corr[4];
        #pragma unroll
        for (int r = 0; r < 4; ++r) {
            float mn = fmaxf(mrow[r], pm[r]);
            corr[r]  = exp2f(mrow[r] - mn);   // exp2f(-inf)=0 on first tile
            mrow[r]  = mn;
        }
        float rs[4];
        #pragma unroll
        for (int r = 0; r < 4; ++r) {
            s0[r] = exp2f(s0[r] - mrow[r]);   // masked: exp2f(-1e30)=0 exactly
            s1[r] = exp2f(s1[r] - mrow[r]);
            rs[r] = s0[r] + s1[r];
        }
        #pragma unroll
        for (int off = 1; off < 16; off <<= 1) {
            #pragma unroll
            for (int r = 0; r < 4; ++r) rs[r] += __shfl_xor(rs[r], off);
        }
        #pragma unroll
        for (int r = 0; r < 4; ++r) lrow[r] = lrow[r] * corr[r] + rs[r];
        #pragma unroll
        for (int t = 0; t < 8; ++t) {
            #pragma unroll
            for (int r = 0; r < 4; ++r) acc[t][r] *= corr[r];
        }

        // ---- P (D-layout) -> LDS -> A-layout for PV ----
        #pragma unroll
        for (int r = 0; r < 4; ++r) {
            int row = 4 * lg + r;
            myP[row * 40 + ln]      = (_Float16)s0[r];
            myP[row * 40 + 16 + ln] = (_Float16)s1[r];
        }
        // same-wave LDS ordering; consumer is a ds_read so the memory clobber orders it
        asm volatile("s_waitcnt lgkmcnt(0)" ::: "memory");

        f16x8 af = *(const f16x8*)(myP + ln * 40 + lg * 8);
        #pragma unroll
        for (int t = 0; t < 8; ++t) {
            f16x8 bf = *(const f16x8*)(&ldsVT[(t * 16 + ln) * 40 + lg * 8]);
            acc[t] = __builtin_amdgcn_mfma_f32_16x16x32_f16(af, bf, acc[t], 0, 0, 0);
        }
    }

    // ---- epilogue: O = acc / l ----
    #pragma unroll
    for (int r = 0; r < 4; ++r) {
        float inv = 1.f / lrow[r];
        float* orow = Og + ((size_t)b * LQ + q0 + 4 * lg + r) * DIM;
        #pragma unroll
        for (int t = 0; t < 8; ++t) orow[t * 16 + ln] = acc[t][r] * inv;
    }
}

extern "C" void kernel_launch(void* const* d_in, const int* in_sizes, int n_in,
                              void* d_out, int out_size, void* d_ws, size_t ws_size,
                              hipStream_t stream) {
    const float* Q  = (const float*)d_in[0];
    const float* K  = (const float*)d_in[1];
    const float* V  = (const float*)d_in[2];
    const int*   VL = (const int*)d_in[3];
    float* O = (float*)d_out;

    dim3 grid(16 * 64);   // 16 batches x 64 q-tiles of 32 rows
    dim3 block(128);      // 2 waves
    fa_kernel<<<grid, block, 0, stream>>>(Q, K, V, VL, O);
}

// Round 3
// 104.532 us; speedup vs baseline: 2.1853x; 2.1853x over previous
//
#include <hip/hip_runtime.h>
#include <hip/hip_fp16.h>

// Flash-attention: B=16, Lq=Lk=2048, D=128, fp32 in/out, per-batch key masking.
// R3 = R2 with cvt_pkrtz type fix: bit-cast __fp16 vector results to _Float16 vectors.
// QTILE=128 (4 waves x 32 rows), KTILE=64, swapped QK^T (lane-local softmax),
// register prefetch of next K/V tile (T14), defer-rescale (T13), grid=256.

typedef _Float16 f16x2 __attribute__((ext_vector_type(2)));
typedef _Float16 f16x4 __attribute__((ext_vector_type(4)));
typedef _Float16 f16x8 __attribute__((ext_vector_type(8)));
typedef __fp16   n16x2 __attribute__((ext_vector_type(2)));
typedef float    f32x4 __attribute__((ext_vector_type(4)));

#define LQ 2048
#define LK 2048
#define DIM 128
#define KT 64          // keys per tile
#define NW 4           // waves per block
#define QW 32          // q-rows per wave (2 x 16-row MFMA subtiles)
#define QTILE (NW*QW)  // 128
#define VSTR 72        // f16 element stride for V^T and P tiles

__device__ __forceinline__ f16x2 cvt2(float a, float b) {
    n16x2 t = __builtin_amdgcn_cvt_pkrtz(a, b);
    return __builtin_bit_cast(f16x2, t);
}

__device__ __forceinline__ f16x8 pk8(float4 a, float4 b) {
    f16x2 p0 = cvt2(a.x, a.y);
    f16x2 p1 = cvt2(a.z, a.w);
    f16x2 p2 = cvt2(b.x, b.y);
    f16x2 p3 = cvt2(b.z, b.w);
    f16x8 r;
    r[0]=p0[0]; r[1]=p0[1]; r[2]=p1[0]; r[3]=p1[1];
    r[4]=p2[0]; r[5]=p2[1]; r[6]=p3[0]; r[7]=p3[1];
    return r;
}

__device__ __forceinline__ float fel(const float4& a, const float4& b, int d) {
    // d is compile-time constant after full unroll -> SROA, no scratch
    const float arr[8] = {a.x,a.y,a.z,a.w,b.x,b.y,b.z,b.w};
    return arr[d];
}

__device__ __forceinline__ void stage_issue(const float* __restrict__ Ksrc,
                                            const float* __restrict__ Vsrc, int tid,
                                            float4 ka[4], float4 kb[4],
                                            float4 va[4], float4 vb[4]) {
    #pragma unroll
    for (int i = 0; i < 4; ++i) {
        int c = tid + i*256, row = c >> 4, d0 = (c & 15) * 8;
        const float* s = Ksrc + row*DIM + d0;
        ka[i] = *(const float4*)s;  kb[i] = *(const float4*)(s+4);
    }
    int kq = tid >> 4, d0 = (tid & 15) * 8;
    #pragma unroll
    for (int j = 0; j < 4; ++j) {
        const float* s = Vsrc + (kq*4 + j)*DIM + d0;
        va[j] = *(const float4*)s;  vb[j] = *(const float4*)(s+4);
    }
}

__device__ __forceinline__ void stage_write(_Float16* ldsK, _Float16* ldsVT, int tid,
                                            const float4 ka[4], const float4 kb[4],
                                            const float4 va[4], const float4 vb[4]) {
    char* kbase = (char*)ldsK;
    #pragma unroll
    for (int i = 0; i < 4; ++i) {
        int c = tid + i*256, row = c >> 4, d0 = (c & 15) * 8;
        // K row-major [64][128] f16, XOR-swizzled within 8-row stripes
        *(f16x8*)(kbase + (((row << 8) + (d0 << 1)) ^ ((row & 7) << 4))) = pk8(ka[i], kb[i]);
    }
    int kq = tid >> 4, d0 = (tid & 15) * 8;
    #pragma unroll
    for (int d = 0; d < 8; ++d) {
        // V^T [d][key], pack 4 consecutive keys -> one ds_write_b64
        f16x2 lo = cvt2(fel(va[0],vb[0],d), fel(va[1],vb[1],d));
        f16x2 hi = cvt2(fel(va[2],vb[2],d), fel(va[3],vb[3],d));
        f16x4 w; w[0]=lo[0]; w[1]=lo[1]; w[2]=hi[0]; w[3]=hi[1];
        *(f16x4*)(ldsVT + (d0 + d)*VSTR + 4*kq) = w;
    }
}

__global__ __launch_bounds__(256, 1)
void fa_kernel(const float* __restrict__ Qg, const float* __restrict__ Kg,
               const float* __restrict__ Vg, const int* __restrict__ VLg,
               float* __restrict__ Og)
{
    __shared__ __align__(16) _Float16 ldsK[KT * DIM];        // 16 KB
    __shared__ __align__(16) _Float16 ldsVT[DIM * VSTR];     // 18 KB
    __shared__ __align__(16) _Float16 ldsP[NW][2][16 * VSTR];// 18 KB

    const int tid = threadIdx.x, wv = tid >> 6, lane = tid & 63;
    const int lg = lane >> 4, ln = lane & 15;
    const int b = blockIdx.x & 15, qt = blockIdx.x >> 4;
    const int q0 = qt * QTILE + wv * QW;
    const int nvalid = VLg[b];                 // 1..2048
    const int nt = (nvalid + KT - 1) / KT;     // skip fully-masked tiles (exact)
    const float SCL = 0.08838834764831845f * 1.44269504088896341f; // 1/sqrt(128)*log2e

    const float* Kb = Kg + (size_t)b * LK * DIM;
    const float* Vb = Vg + (size_t)b * LK * DIM;

    // Q fragments (B-operand of swapped QK, also scaled): qf[qs][dc]
    f16x8 qf[2][4];
    #pragma unroll
    for (int qs = 0; qs < 2; ++qs) {
        const float* qr = Qg + ((size_t)b*LQ + q0 + qs*16 + ln)*DIM + lg*8;
        #pragma unroll
        for (int dc = 0; dc < 4; ++dc) {
            float4 a = *(const float4*)(qr + dc*32);
            float4 c = *(const float4*)(qr + dc*32 + 4);
            a.x*=SCL; a.y*=SCL; a.z*=SCL; a.w*=SCL;
            c.x*=SCL; c.y*=SCL; c.z*=SCL; c.w*=SCL;
            qf[qs][dc] = pk8(a, c);
        }
    }

    float4 ka[4], kb4[4], va[4], vb[4];
    stage_issue(Kb, Vb, tid, ka, kb4, va, vb);
    stage_write(ldsK, ldsVT, tid, ka, kb4, va, vb);
    __syncthreads();

    f32x4 acc[2][8];
    #pragma unroll
    for (int qs = 0; qs < 2; ++qs)
        #pragma unroll
        for (int t = 0; t < 8; ++t) acc[qs][t] = (f32x4){0.f,0.f,0.f,0.f};
    float mrow[2] = {-__builtin_inff(), -__builtin_inff()};
    float lrow[2] = {0.f, 0.f};

    _Float16* myP0 = &ldsP[wv][0][0];
    _Float16* myP1 = &ldsP[wv][1][0];
    char* kbase = (char*)ldsK;

    for (int t = 0; t < nt; ++t) {
        const int k0 = t * KT;
        const bool more = (t + 1 < nt);
        if (more)  // T14: issue next tile's global loads; waits land at stage_write
            stage_issue(Kb + (size_t)(k0+KT)*DIM, Vb + (size_t)(k0+KT)*DIM, tid, ka, kb4, va, vb);

        // ---- swapped QK^T: s = mfma(K_chunk, Q) -> D[key][q], q = ln lane-local ----
        f32x4 s[2][4];
        #pragma unroll
        for (int qs = 0; qs < 2; ++qs)
            #pragma unroll
            for (int kc = 0; kc < 4; ++kc) s[qs][kc] = (f32x4){0.f,0.f,0.f,0.f};
        #pragma unroll
        for (int kc = 0; kc < 4; ++kc) {
            #pragma unroll
            for (int dc = 0; dc < 4; ++dc) {
                f16x8 kf = *(const f16x8*)(kbase +
                    ((((kc*16 + ln) << 8) + dc*64 + lg*16) ^ ((ln & 7) << 4)));
                s[0][kc] = __builtin_amdgcn_mfma_f32_16x16x32_f16(kf, qf[0][dc], s[0][kc], 0,0,0);
                s[1][kc] = __builtin_amdgcn_mfma_f32_16x16x32_f16(kf, qf[1][dc], s[1][kc], 0,0,0);
            }
        }

        // ---- boundary mask (last tile only): key index = k0 + kc*16 + 4*lg + r ----
        if (k0 + KT > nvalid) {
            #pragma unroll
            for (int kc = 0; kc < 4; ++kc)
                #pragma unroll
                for (int r = 0; r < 4; ++r)
                    if (k0 + kc*16 + 4*lg + r >= nvalid) { s[0][kc][r] = -1e30f; s[1][kc][r] = -1e30f; }
        }

        // ---- online softmax: lane holds 16 k-vals of q-row ln; reduce in-lane + 2 shuffles ----
        #pragma unroll
        for (int qs = 0; qs < 2; ++qs) {
            float pm = s[qs][0][0];
            #pragma unroll
            for (int kc = 0; kc < 4; ++kc)
                #pragma unroll
                for (int r = 0; r < 4; ++r) pm = fmaxf(pm, s[qs][kc][r]);
            pm = fmaxf(pm, __shfl_xor(pm, 16));
            pm = fmaxf(pm, __shfl_xor(pm, 32));

            if (__any(pm > mrow[qs])) {        // T13: skip rescale when max didn't grow
                float mn   = fmaxf(mrow[qs], pm);
                float corr = __builtin_amdgcn_exp2f(mrow[qs] - mn);  // exp2(-inf)=0 first tile
                mrow[qs] = mn;
                lrow[qs] *= corr;
                // transpose corr from q=ln domain to acc row domain q=4*lg+r
                float cr0 = __shfl(corr, 4*lg+0), cr1 = __shfl(corr, 4*lg+1);
                float cr2 = __shfl(corr, 4*lg+2), cr3 = __shfl(corr, 4*lg+3);
                #pragma unroll
                for (int tt = 0; tt < 8; ++tt) {
                    acc[qs][tt][0]*=cr0; acc[qs][tt][1]*=cr1;
                    acc[qs][tt][2]*=cr2; acc[qs][tt][3]*=cr3;
                }
            }

            float rs = 0.f;
            _Float16* myP = qs ? myP1 : myP0;
            #pragma unroll
            for (int kc = 0; kc < 4; ++kc) {
                float p0 = __builtin_amdgcn_exp2f(s[qs][kc][0] - mrow[qs]); // masked -> exact 0
                float p1 = __builtin_amdgcn_exp2f(s[qs][kc][1] - mrow[qs]);
                float p2 = __builtin_amdgcn_exp2f(s[qs][kc][2] - mrow[qs]);
                float p3 = __builtin_amdgcn_exp2f(s[qs][kc][3] - mrow[qs]);
                rs += (p0 + p1) + (p2 + p3);
                f16x2 lo = cvt2(p0, p1);
                f16x2 hi = cvt2(p2, p3);
                f16x4 w; w[0]=lo[0]; w[1]=lo[1]; w[2]=hi[0]; w[3]=hi[1];
                *(f16x4*)(myP + ln*VSTR + kc*16 + 4*lg) = w;   // P[q=ln][k], 4 consecutive k
            }
            rs += __shfl_xor(rs, 16);
            rs += __shfl_xor(rs, 32);
            lrow[qs] += rs;
        }

        asm volatile("s_waitcnt lgkmcnt(0)" ::: "memory");  // P writes -> af reads (same wave)

        // ---- PV: acc[qs][tt] += P[qs] (A) x V (B) ----
        f16x8 af[2][2];
        #pragma unroll
        for (int qs = 0; qs < 2; ++qs) {
            _Float16* myP = qs ? myP1 : myP0;
            #pragma unroll
            for (int kc2 = 0; kc2 < 2; ++kc2)
                af[qs][kc2] = *(const f16x8*)(myP + ln*VSTR + kc2*32 + lg*8);
        }
        #pragma unroll
        for (int tt = 0; tt < 8; ++tt) {
            #pragma unroll
            for (int kc2 = 0; kc2 < 2; ++kc2) {
                f16x8 bf = *(const f16x8*)(&ldsVT[(tt*16 + ln)*VSTR + kc2*32 + lg*8]);
                acc[0][tt] = __builtin_amdgcn_mfma_f32_16x16x32_f16(af[0][kc2], bf, acc[0][tt], 0,0,0);
                acc[1][tt] = __builtin_amdgcn_mfma_f32_16x16x32_f16(af[1][kc2], bf, acc[1][tt], 0,0,0);
            }
        }

        if (more) {
            __syncthreads();                                   // all waves done reading tile t
            stage_write(ldsK, ldsVT, tid, ka, kb4, va, vb);    // vmcnt waits auto-inserted here
            __syncthreads();                                   // tile t+1 visible
        }
    }

    // ---- epilogue: O = acc / l ----
    #pragma unroll
    for (int qs = 0; qs < 2; ++qs) {
        float linv = 1.f / lrow[qs];
        float l0 = __shfl(linv, 4*lg+0), l1 = __shfl(linv, 4*lg+1);
        float l2 = __shfl(linv, 4*lg+2), l3 = __shfl(linv, 4*lg+3);
        const float lr[4] = {l0, l1, l2, l3};
        #pragma unroll
        for (int r = 0; r < 4; ++r) {
            float* orow = Og + ((size_t)b*LQ + q0 + qs*16 + 4*lg + r)*DIM + ln;
            #pragma unroll
            for (int tt = 0; tt < 8; ++tt) orow[tt*16] = acc[qs][tt][r] * lr[r];
        }
    }
}

extern "C" void kernel_launch(void* const* d_in, const int* in_sizes, int n_in,
                              void* d_out, int out_size, void* d_ws, size_t ws_size,
                              hipStream_t stream) {
    const float* Q  = (const float*)d_in[0];
    const float* K  = (const float*)d_in[1];
    const float* V  = (const float*)d_in[2];
    const int*   VL = (const int*)d_in[3];
    float* O = (float*)d_out;

    dim3 grid(16 * 16);   // b = blk&15 (batch-mixed), qt = blk>>4
    dim3 block(256);      // 4 waves x 32 q-rows = 128-row Q tile
    fa_kernel<<<grid, block, 0, stream>>>(Q, K, V, VL, O);
}

// Round 4
// 71.004 us; speedup vs baseline: 3.2172x; 1.4722x over previous
//
#include <hip/hip_runtime.h>
#include <hip/hip_fp16.h>

// Flash-attention: B=16, Lq=Lk=2048, D=128, fp32 in/out, per-batch key masking.
// R4: QTILE=64 (4 waves x 16 rows), grid=512 -> 2 blocks/CU (TLP latency hiding);
// V^T stored [128][64] with (row^(row>>3))&7 16B-block XOR swizzle (kills the
// 16-way write conflict of the old VSTR=72 pad); setprio around MFMA clusters.

typedef _Float16 f16x2 __attribute__((ext_vector_type(2)));
typedef _Float16 f16x4 __attribute__((ext_vector_type(4)));
typedef _Float16 f16x8 __attribute__((ext_vector_type(8)));
typedef __fp16   n16x2 __attribute__((ext_vector_type(2)));
typedef float    f32x4 __attribute__((ext_vector_type(4)));

#define LQ 2048
#define LK 2048
#define DIM 128
#define KT 64          // keys per tile
#define NW 4           // waves per block
#define QW 16          // q-rows per wave (one 16-row MFMA subtile)
#define QTILE (NW*QW)  // 64
#define PSTR 72        // f16 element stride for P tile rows

__device__ __forceinline__ f16x2 cvt2(float a, float b) {
    n16x2 t = __builtin_amdgcn_cvt_pkrtz(a, b);
    return __builtin_bit_cast(f16x2, t);
}

__device__ __forceinline__ f16x8 pk8(float4 a, float4 b) {
    f16x2 p0 = cvt2(a.x, a.y), p1 = cvt2(a.z, a.w);
    f16x2 p2 = cvt2(b.x, b.y), p3 = cvt2(b.z, b.w);
    f16x8 r;
    r[0]=p0[0]; r[1]=p0[1]; r[2]=p1[0]; r[3]=p1[1];
    r[4]=p2[0]; r[5]=p2[1]; r[6]=p3[0]; r[7]=p3[1];
    return r;
}

__device__ __forceinline__ float fel(const float4& a, const float4& b, int d) {
    const float arr[8] = {a.x,a.y,a.z,a.w,b.x,b.y,b.z,b.w};
    return arr[d];
}

// V^T byte offset: rows = d (128), cols = key (64, 128B/row), XOR-swizzled 16B blocks
__device__ __forceinline__ int vt_off(int d, int k) {
    return d*128 + (((k >> 3) ^ ((d ^ (d >> 3)) & 7)) << 4) + (k & 7) * 2;
}

__device__ __forceinline__ void stage_issue(const float* __restrict__ Ksrc,
                                            const float* __restrict__ Vsrc, int tid,
                                            float4 ka[4], float4 kb[4],
                                            float4 va[4], float4 vb[4]) {
    #pragma unroll
    for (int i = 0; i < 4; ++i) {
        int c = tid + i*256, row = c >> 4, d0 = (c & 15) * 8;
        const float* s = Ksrc + row*DIM + d0;
        ka[i] = *(const float4*)s;  kb[i] = *(const float4*)(s+4);
    }
    int kq = tid >> 4, d0 = (tid & 15) * 8;
    #pragma unroll
    for (int j = 0; j < 4; ++j) {
        const float* s = Vsrc + (kq*4 + j)*DIM + d0;
        va[j] = *(const float4*)s;  vb[j] = *(const float4*)(s+4);
    }
}

__device__ __forceinline__ void stage_write(_Float16* ldsK, _Float16* ldsVT, int tid,
                                            const float4 ka[4], const float4 kb[4],
                                            const float4 va[4], const float4 vb[4]) {
    char* kbase = (char*)ldsK;
    #pragma unroll
    for (int i = 0; i < 4; ++i) {
        int c = tid + i*256, row = c >> 4, d0 = (c & 15) * 8;
        // K row-major [64][128] f16, XOR-swizzled within 8-row stripes
        *(f16x8*)(kbase + (((row << 8) + (d0 << 1)) ^ ((row & 7) << 4))) = pk8(ka[i], kb[i]);
    }
    char* vbase = (char*)ldsVT;
    int kq = tid >> 4, d0 = (tid & 15) * 8;
    #pragma unroll
    for (int dd = 0; dd < 8; ++dd) {
        int row = d0 + dd;
        f16x2 lo = cvt2(fel(va[0],vb[0],dd), fel(va[1],vb[1],dd));
        f16x2 hi = cvt2(fel(va[2],vb[2],dd), fel(va[3],vb[3],dd));
        f16x4 w; w[0]=lo[0]; w[1]=lo[1]; w[2]=hi[0]; w[3]=hi[1];
        *(f16x4*)(vbase + vt_off(row, 4*kq)) = w;
    }
}

__global__ __launch_bounds__(256, 2)
void fa_kernel(const float* __restrict__ Qg, const float* __restrict__ Kg,
               const float* __restrict__ Vg, const int* __restrict__ VLg,
               float* __restrict__ Og)
{
    __shared__ __align__(16) _Float16 ldsK[KT * DIM];        // 16 KB
    __shared__ __align__(16) _Float16 ldsVT[DIM * 64];       // 16 KB (swizzled)
    __shared__ __align__(16) _Float16 ldsP[NW][16 * PSTR];   // 9 KB

    const int tid = threadIdx.x, wv = tid >> 6, lane = tid & 63;
    const int lg = lane >> 4, ln = lane & 15;
    const int b = blockIdx.x & 15, qt = blockIdx.x >> 4;
    const int q0 = qt * QTILE + wv * QW;
    const int nvalid = VLg[b];                 // 1..2048
    const int nt = (nvalid + KT - 1) / KT;     // skip fully-masked tiles (exact)
    const float SCL = 0.08838834764831845f * 1.44269504088896341f; // 1/sqrt(128)*log2e

    const float* Kb = Kg + (size_t)b * LK * DIM;
    const float* Vb = Vg + (size_t)b * LK * DIM;

    // Q fragments (B-operand of swapped QK, pre-scaled): qf[dc]
    f16x8 qf[4];
    {
        const float* qr = Qg + ((size_t)b*LQ + q0 + ln)*DIM + lg*8;
        #pragma unroll
        for (int dc = 0; dc < 4; ++dc) {
            float4 a = *(const float4*)(qr + dc*32);
            float4 c = *(const float4*)(qr + dc*32 + 4);
            a.x*=SCL; a.y*=SCL; a.z*=SCL; a.w*=SCL;
            c.x*=SCL; c.y*=SCL; c.z*=SCL; c.w*=SCL;
            qf[dc] = pk8(a, c);
        }
    }

    float4 ka[4], kb4[4], va[4], vb[4];
    stage_issue(Kb, Vb, tid, ka, kb4, va, vb);
    stage_write(ldsK, ldsVT, tid, ka, kb4, va, vb);
    __syncthreads();

    f32x4 acc[8];
    #pragma unroll
    for (int t = 0; t < 8; ++t) acc[t] = (f32x4){0.f,0.f,0.f,0.f};
    float mrow = -__builtin_inff();
    float lrow = 0.f;

    _Float16* myP = &ldsP[wv][0];
    char* kbase = (char*)ldsK;
    char* vbase = (char*)ldsVT;

    for (int t = 0; t < nt; ++t) {
        const int k0 = t * KT;
        const bool more = (t + 1 < nt);
        if (more)  // T14: issue next tile's global loads; waits land at stage_write
            stage_issue(Kb + (size_t)(k0+KT)*DIM, Vb + (size_t)(k0+KT)*DIM, tid, ka, kb4, va, vb);

        // ---- swapped QK^T: s = mfma(K_chunk, Q) -> D[key][q], q = ln lane-local ----
        f32x4 s[4];
        #pragma unroll
        for (int kc = 0; kc < 4; ++kc) s[kc] = (f32x4){0.f,0.f,0.f,0.f};
        __builtin_amdgcn_s_setprio(1);
        #pragma unroll
        for (int kc = 0; kc < 4; ++kc) {
            #pragma unroll
            for (int dc = 0; dc < 4; ++dc) {
                f16x8 kf = *(const f16x8*)(kbase +
                    ((((kc*16 + ln) << 8) + dc*64 + lg*16) ^ ((ln & 7) << 4)));
                s[kc] = __builtin_amdgcn_mfma_f32_16x16x32_f16(kf, qf[dc], s[kc], 0,0,0);
            }
        }
        __builtin_amdgcn_s_setprio(0);

        // ---- boundary mask (last tile only): key index = k0 + kc*16 + 4*lg + r ----
        if (k0 + KT > nvalid) {
            #pragma unroll
            for (int kc = 0; kc < 4; ++kc)
                #pragma unroll
                for (int r = 0; r < 4; ++r)
                    if (k0 + kc*16 + 4*lg + r >= nvalid) s[kc][r] = -1e30f;
        }

        // ---- online softmax: lane holds 16 k-vals of q-row ln; in-lane + 2 shuffles ----
        float pm = s[0][0];
        #pragma unroll
        for (int kc = 0; kc < 4; ++kc)
            #pragma unroll
            for (int r = 0; r < 4; ++r) pm = fmaxf(pm, s[kc][r]);
        pm = fmaxf(pm, __shfl_xor(pm, 16));
        pm = fmaxf(pm, __shfl_xor(pm, 32));

        if (__any(pm > mrow)) {            // T13: skip rescale when max didn't grow
            float mn   = fmaxf(mrow, pm);
            float corr = __builtin_amdgcn_exp2f(mrow - mn);  // exp2(-inf)=0 first tile
            mrow = mn;
            lrow *= corr;
            float cr0 = __shfl(corr, 4*lg+0), cr1 = __shfl(corr, 4*lg+1);
            float cr2 = __shfl(corr, 4*lg+2), cr3 = __shfl(corr, 4*lg+3);
            #pragma unroll
            for (int tt = 0; tt < 8; ++tt) {
                acc[tt][0]*=cr0; acc[tt][1]*=cr1;
                acc[tt][2]*=cr2; acc[tt][3]*=cr3;
            }
        }

        float rs = 0.f;
        #pragma unroll
        for (int kc = 0; kc < 4; ++kc) {
            float p0 = __builtin_amdgcn_exp2f(s[kc][0] - mrow);  // masked -> exact 0
            float p1 = __builtin_amdgcn_exp2f(s[kc][1] - mrow);
            float p2 = __builtin_amdgcn_exp2f(s[kc][2] - mrow);
            float p3 = __builtin_amdgcn_exp2f(s[kc][3] - mrow);
            rs += (p0 + p1) + (p2 + p3);
            f16x2 lo = cvt2(p0, p1);
            f16x2 hi = cvt2(p2, p3);
            f16x4 w; w[0]=lo[0]; w[1]=lo[1]; w[2]=hi[0]; w[3]=hi[1];
            *(f16x4*)(myP + ln*PSTR + kc*16 + 4*lg) = w;   // P[q=ln][k], 4 consecutive k
        }
        rs += __shfl_xor(rs, 16);
        rs += __shfl_xor(rs, 32);
        lrow += rs;

        asm volatile("s_waitcnt lgkmcnt(0)" ::: "memory");  // P writes -> af reads (same wave)

        // ---- PV: acc[tt] += P (A) x V (B) ----
        f16x8 af[2];
        #pragma unroll
        for (int kc2 = 0; kc2 < 2; ++kc2)
            af[kc2] = *(const f16x8*)(myP + ln*PSTR + kc2*32 + lg*8);
        __builtin_amdgcn_s_setprio(1);
        #pragma unroll
        for (int tt = 0; tt < 8; ++tt) {
            #pragma unroll
            for (int kc2 = 0; kc2 < 2; ++kc2) {
                f16x8 bf = *(const f16x8*)(vbase + vt_off(tt*16 + ln, kc2*32 + lg*8));
                acc[tt] = __builtin_amdgcn_mfma_f32_16x16x32_f16(af[kc2], bf, acc[tt], 0,0,0);
            }
        }
        __builtin_amdgcn_s_setprio(0);

        if (more) {
            __syncthreads();                                   // all waves done reading tile t
            stage_write(ldsK, ldsVT, tid, ka, kb4, va, vb);    // vmcnt waits auto-inserted here
            __syncthreads();                                   // tile t+1 visible
        }
    }

    // ---- epilogue: O = acc / l ----
    {
        float linv = 1.f / lrow;
        float l0 = __shfl(linv, 4*lg+0), l1 = __shfl(linv, 4*lg+1);
        float l2 = __shfl(linv, 4*lg+2), l3 = __shfl(linv, 4*lg+3);
        const float lr[4] = {l0, l1, l2, l3};
        #pragma unroll
        for (int r = 0; r < 4; ++r) {
            float* orow = Og + ((size_t)b*LQ + q0 + 4*lg + r)*DIM + ln;
            #pragma unroll
            for (int tt = 0; tt < 8; ++tt) orow[tt*16] = acc[tt][r] * lr[r];
        }
    }
}

extern "C" void kernel_launch(void* const* d_in, const int* in_sizes, int n_in,
                              void* d_out, int out_size, void* d_ws, size_t ws_size,
                              hipStream_t stream) {
    const float* Q  = (const float*)d_in[0];
    const float* K  = (const float*)d_in[1];
    const float* V  = (const float*)d_in[2];
    const int*   VL = (const int*)d_in[3];
    float* O = (float*)d_out;

    dim3 grid(16 * 32);   // b = blk&15 (same batch -> same XCD L2), qt = blk>>4
    dim3 block(256);      // 4 waves x 16 q-rows = 64-row Q tile
    fa_kernel<<<grid, block, 0, stream>>>(Q, K, V, VL, O);
}